// Round 9
// baseline (105.471 us; speedup 1.0000x reference)
//
#include <hip/hip_runtime.h>
#include <hip/hip_bf16.h>

typedef unsigned short u16;
typedef unsigned int   u32;
typedef float f32x4  __attribute__((ext_vector_type(4)));
typedef short bf16x8 __attribute__((ext_vector_type(8)));

#define DI __device__ __forceinline__

constexpr int TBL  = 2535;     // (2*8-1)*(2*7-1)*(2*7-1)
constexpr int NTOK = 50176;    // 128 windows * 392 tokens
constexpr float L2E = 1.4426950408889634f;

// bf16 weight scratch layout (u16 units)
constexpr int WB_QW = 0;          // 49152
constexpr int WB_PW = 49152;      // 16384
constexpr int WB_QB = 65536;      // 384
constexpr int WB_PB = 65920;      // 128
constexpr int WB_TOT = 66048;

DI float b2f(u16 u){ return __uint_as_float(((u32)u)<<16); }
DI u16 f2b(float f){
  u32 u = __float_as_uint(f);
  return (u16)((u + 0x7fffu + ((u>>16)&1u)) >> 16);
}
DI float ldf(const void* p, int i, int isf32){
  return isf32 ? ((const float*)p)[i] : b2f(((const u16*)p)[i]);
}
DI f32x4 mfma16(bf16x8 a, bf16x8 b, f32x4 c){
  return __builtin_amdgcn_mfma_f32_16x16x32_bf16(a, b, c, 0, 0, 0);
}
DI u32 cvtpk(float lo, float hi){
  u32 r;
  asm("v_cvt_pk_bf16_f32 %0, %1, %2" : "=v"(r) : "v"(lo), "v"(hi));
  return r;
}
DI float vexp2(float x){
  float r;
  asm("v_exp_f32 %0, %1" : "=v"(r) : "v"(x));
  return r;
}
// per-wave dtype self-detect: low u16 of 64 words of x viewed as bf16.
DI int detect_f32(const void* x, int lane){
  u32 w = ((const u32*)x)[lane];
  u16 lo = (u16)w;
  u32 e = (lo >> 7) & 0xFF;
  int wild = (lo != 0 && (e >= 143 || e <= 111)) ? 1 : 0;
  unsigned long long m = __ballot(wild);
  return __popcll(m) > 16;
}

// ---------------- 1) CPB MLP table (value = (16*sigmoid - 15) * log2(e))
__global__ void k_cpb(const void* __restrict__ w1, const void* __restrict__ b1,
                      const void* __restrict__ w2, const void* __restrict__ x,
                      const void* __restrict__ qw, const void* __restrict__ pw,
                      const void* __restrict__ qb, const void* __restrict__ pb,
                      u16* __restrict__ wb, float* __restrict__ table16){
  const int lane = threadIdx.x;
  const int isf32 = detect_f32(x, lane);
  { // merged weight conversion
    int gid = blockIdx.x*64 + lane;
    if (gid < WB_TOT){
      const void* src; int off;
      if (gid < WB_PW)      { src = qw; off = gid; }
      else if (gid < WB_QB) { src = pw; off = gid - WB_PW; }
      else if (gid < WB_PB) { src = qb; off = gid - WB_QB; }
      else                  { src = pb; off = gid - WB_PB; }
      wb[gid] = isf32 ? f2b(((const float*)src)[off]) : ((const u16*)src)[off];
    }
  }
  int t = blockIdx.x;
  int i = t/169; int r = t - i*169; int j = r/13; int k = r - j*13;
  float v0 = 8.f*(float)(i-7)/7.f, v1 = 8.f*(float)(j-6)/6.f, v2 = 8.f*(float)(k-6)/6.f;
  float c0 = copysignf(log2f(fabsf(v0)+1.f)*(1.f/3.f), v0);
  float c1 = copysignf(log2f(fabsf(v1)+1.f)*(1.f/3.f), v1);
  float c2 = copysignf(log2f(fabsf(v2)+1.f)*(1.f/3.f), v2);
  float a0=0.f,a1=0.f,a2=0.f,a3=0.f;
  for (int hh = lane; hh < 512; hh += 64){
    float a = c0*ldf(w1,hh*3,isf32) + c1*ldf(w1,hh*3+1,isf32)
            + c2*ldf(w1,hh*3+2,isf32) + ldf(b1,hh,isf32);
    a = fmaxf(a, 0.f);
    a0 += a*ldf(w2,hh,isf32);       a1 += a*ldf(w2,512+hh,isf32);
    a2 += a*ldf(w2,1024+hh,isf32);  a3 += a*ldf(w2,1536+hh,isf32);
  }
  #pragma unroll
  for (int off=32; off; off>>=1){
    a0 += __shfl_xor(a0, off); a1 += __shfl_xor(a1, off);
    a2 += __shfl_xor(a2, off); a3 += __shfl_xor(a3, off);
  }
  if (lane==0){
    table16[t]       = (16.f/(1.f+__expf(-a0)) - 15.f)*L2E;
    table16[TBL+t]   = (16.f/(1.f+__expf(-a1)) - 15.f)*L2E;
    table16[2*TBL+t] = (16.f/(1.f+__expf(-a2)) - 15.f)*L2E;
    table16[3*TBL+t] = (16.f/(1.f+__expf(-a3)) - 15.f)*L2E;
  }
}

// ---------------- 2) expand to bias16[h][n][m] (f32, pre-scaled by log2e)
__global__ void k_bias(const float* __restrict__ table16, float* __restrict__ bias16){
  int n = blockIdx.x, h = blockIdx.y;
  int td = n/49; int r2 = n - td*49; int th = r2/7; int tw = r2 - th*7;
  const float* tb = table16 + h*TBL;
  float* o = bias16 + ((size_t)h*392 + n)*392;
  for (int m = threadIdx.x; m < 392; m += 128){
    int sd = m/49; int q2 = m - sd*49; int sh = q2/7; int sw = q2 - sh*7;
    int idx = (td - sd + 7)*169 + (th - sh + 6)*13 + (tw - sw + 6);
    o[m] = tb[idx];
  }
}

// ---------------- 3) QKV GEMM via MFMA + fused Q/K row-normalization
//                    + coalesced epilogue via LDS bounce
__global__ __launch_bounds__(256,3) void k_qkv(const void* __restrict__ x,
    const u16* __restrict__ wb, const void* __restrict__ lsc,
    u16* __restrict__ qkvbuf){
  __shared__ __align__(16) u16 As[64*136];   // [tok][k] / output bounce
  __shared__ __align__(16) u16 Ws[128*136];  // [oc][k]
  const int tid = threadIdx.x;
  const int lane = tid & 63;
  const int isf32 = detect_f32(x, lane);
  const int tokbase0 = blockIdx.x*64;
  { // stage x rows (gather through roll+window mapping)
    int trow = tid>>2, cq = (tid&3)*32;
    int gtok = tokbase0 + trow;
    int win = gtok/392, tt = gtok - win*392;
    int dwi = win>>6, hwi = (win>>3)&7, wwi = win&7;
    int td = tt/49; int r2 = tt - td*49; int th = r2/7; int tw = r2 - th*7;
    int pd = dwi*8 + td + 4; if (pd >= 16) pd -= 16;
    int ph = hwi*7 + th + 3; if (ph >= 56) ph -= 56;
    int pw = wwi*7 + tw + 3; if (pw >= 56) pw -= 56;
    size_t pos = (size_t)((pd*56 + ph)*56 + pw)*128 + cq;
    if (isf32){
      const float4* src = (const float4*)((const float*)x + pos);
      #pragma unroll
      for (int u=0; u<8; ++u){
        float4 a = src[u];
        ushort4 s4 = make_ushort4(f2b(a.x), f2b(a.y), f2b(a.z), f2b(a.w));
        *(ushort4*)&As[trow*136 + cq + u*4] = s4;
      }
    } else {
      const uint4* src = (const uint4*)((const u16*)x + pos);
      #pragma unroll
      for (int u=0; u<4; ++u) *(uint4*)&As[trow*136 + cq + u*8] = src[u];
    }
  }
  const int wave = tid>>6;
  const int c = lane & 15, g = lane >> 4;
  // per-head scale*log2e
  float sl2e[4];
  #pragma unroll
  for (int h2=0; h2<4; ++h2){
    float ls = ldf(lsc, h2, isf32);
    sl2e[h2] = __expf(fminf(ls, 4.60517019f)) * L2E;
  }
  bf16x8 ka[4];
  for (int which = 0; which < 3; ++which){
    __syncthreads();   // (A) prev bounce reads done / As ready (first pass)
    { // stage weight rows [which*128 .. +127] (bf16 preconverted)
      int orow = tid>>1, c2 = (tid&1)*64;
      const uint4* src = (const uint4*)(wb + WB_QW + (size_t)(which*128 + orow)*128 + c2);
      #pragma unroll
      for (int u=0; u<8; ++u) *(uint4*)&Ws[orow*136 + c2 + u*8] = src[u];
    }
    __syncthreads();   // (B) Ws ready
    if (which == 0){
      #pragma unroll
      for (int kk=0; kk<4; ++kk)
        ka[kk] = *(const bf16x8*)&As[(wave*16 + c)*136 + kk*32 + g*8];
    }
    f32x4 acc[8];
    #pragma unroll
    for (int nt=0; nt<8; ++nt) acc[nt] = 0.f;
    #pragma unroll
    for (int nt=0; nt<8; ++nt){
      #pragma unroll
      for (int kk=0; kk<4; ++kk){
        bf16x8 wf = *(const bf16x8*)&Ws[(nt*16 + c)*136 + kk*32 + g*8];
        acc[nt] = mfma16(ka[kk], wf, acc[nt]);
      }
    }
    // add bias (k-bias zeroed per Swin v2)
    if (which != 1){
      #pragma unroll
      for (int nt=0; nt<8; ++nt){
        float bv = b2f(wb[WB_QB + which*128 + nt*16 + c]);
        #pragma unroll
        for (int r=0;r<4;++r) acc[nt][r] += bv;
      }
    }
    // row-normalize q/k per head (reduce over the 16 c-lanes)
    if (which < 2){
      #pragma unroll
      for (int h2=0; h2<4; ++h2){
        f32x4 ss;
        #pragma unroll
        for (int r=0;r<4;++r)
          ss[r] = acc[2*h2][r]*acc[2*h2][r] + acc[2*h2+1][r]*acc[2*h2+1][r];
        #pragma unroll
        for (int off=1; off<16; off<<=1){
          #pragma unroll
          for (int r=0;r<4;++r) ss[r] += __shfl_xor(ss[r], off);
        }
        #pragma unroll
        for (int r=0;r<4;++r){
          float rn = rsqrtf(fmaxf(ss[r], 1e-24f));
          if (which == 0) rn *= sl2e[h2];
          acc[2*h2][r]   *= rn;
          acc[2*h2+1][r] *= rn;
        }
      }
    }
    __syncthreads();   // (C) all ka/As reads done -> As reusable as bounce
    #pragma unroll
    for (int nt=0; nt<8; ++nt){
      #pragma unroll
      for (int r=0;r<4;++r)
        As[(wave*16 + 4*g + r)*136 + nt*16 + c] = f2b(acc[nt][r]);
    }
    __syncthreads();   // (D) bounce ready
    { // coalesced store: 4x uint4 per thread
      const int tokl = tid>>2, seg = tid&3;
      u16* dst = qkvbuf + ((size_t)(which*4+seg)*NTOK + tokbase0 + tokl)*32;
      const u16* srcl = &As[tokl*136 + seg*32];
      #pragma unroll
      for (int u=0; u<4; ++u)
        *(uint4*)(dst + u*8) = *(const uint4*)(srcl + u*8);
    }
  }
}

// ---------------- 4) attention: paired Q-tiles + 1-step K/bias prefetch pipeline
DI bf16x8 ldK(const u16* klds, int jt, int c, int g){
  return *(const bf16x8*)&klds[(jt*16 + c)*40 + g*8];
}
DI float4 ldB(const float* brow, int jt, int g){
  int mbc = jt*16 + 4*g; if (mbc > 388) mbc = 388;
  return *(const float4*)(brow + mbc);
}
DI int4 ldC(const int* cnt, int jt, int g){
  int mbc = jt*16 + 4*g; if (mbc > 388) mbc = 388;
  return *(const int4*)&cnt[mbc];
}

#define QKT_BODY(JJ, TAIL, KF, BA, BB, CM, JT) do { \
  f32x4 tz = {0.f,0.f,0.f,0.f}; \
  f32x4 ta = mfma16(KF, qfa, tz); \
  f32x4 tb = mfma16(KF, qfb, tz); \
  float pa0 = vexp2(ta[0] + BA.x), pa1 = vexp2(ta[1] + BA.y); \
  float pa2 = vexp2(ta[2] + BA.z), pa3 = vexp2(ta[3] + BA.w); \
  float pb0 = vexp2(tb[0] + BB.x), pb1 = vexp2(tb[1] + BB.y); \
  float pb2 = vexp2(tb[2] + BB.z), pb3 = vexp2(tb[3] + BB.w); \
  if (MIXED){ \
    if (CM.x != cnA) pa0 = 0.f;  if (CM.y != cnA) pa1 = 0.f; \
    if (CM.z != cnA) pa2 = 0.f;  if (CM.w != cnA) pa3 = 0.f; \
    if (CM.x != cnB) pb0 = 0.f;  if (CM.y != cnB) pb1 = 0.f; \
    if (CM.z != cnB) pb2 = 0.f;  if (CM.w != cnB) pb3 = 0.f; \
  } \
  if (TAIL){ \
    const int mb = (JT)*16 + 4*g; \
    if (mb > 388){ pa0=0.f; pa1=0.f; pa2=0.f; pa3=0.f; \
                   pb0=0.f; pb1=0.f; pb2=0.f; pb3=0.f; } \
  } \
  uint2 wva, wvb; \
  wva.x = cvtpk(pa0,pa1); wva.y = cvtpk(pa2,pa3); \
  wvb.x = cvtpk(pb0,pb1); wvb.y = cvtpk(pb2,pb3); \
  *(uint2*)&psA[c*20 + (JJ)*8 + 2*g] = wva; \
  *(uint2*)&psB[c*20 + (JJ)*8 + 2*g] = wvb; \
} while(0)

#define PV_PAIR(MC) do { \
  bf16x8 pfa = *(const bf16x8*)&psA[c*20 + 4*g]; \
  bf16x8 pfb = *(const bf16x8*)&psB[c*20 + 4*g]; \
  bf16x8 va = *(const bf16x8*)&vT[c*424 + (MC)*32 + g*8]; \
  bf16x8 vb = *(const bf16x8*)&vT[(16+c)*424 + (MC)*32 + g*8]; \
  o0a = mfma16(va, pfa, o0a); o1a = mfma16(vb, pfa, o1a); o2a = mfma16(ones, pfa, o2a); \
  o0b = mfma16(va, pfb, o0b); o1b = mfma16(vb, pfb, o1b); o2b = mfma16(ones, pfb, o2b); \
} while(0)

template<bool MIXED>
DI void attn_main(const u16* __restrict__ qg, const float* __restrict__ bias_h,
                  const u16* klds, const u16* vT, u32* psA, u32* psB, const int* cnt,
                  u16* __restrict__ aout, int win, int h, int wave, int lane){
  const int c = lane & 15, g = lane >> 4;
  const short ob = 0x3F80;
  const bf16x8 ones = {ob,ob,ob,ob,ob,ob,ob,ob};
  const int4 zc = {0,0,0,0};
  for (int pp = wave; pp < 13; pp += 8){
    const int rta = 2*pp;
    const int rtb = (pp < 12) ? (2*pp+1) : 24;
    const bool hasB = (pp < 12);
    const int nbA = rta*16, nbB = rtb*16;
    const int ncA = (nbA + c < 392) ? (nbA + c) : 391;
    const int ncB = (nbB + c < 392) ? (nbB + c) : 391;
    const bf16x8 qfa = *(const bf16x8*)(qg + (size_t)ncA*32 + g*8);
    const bf16x8 qfb = *(const bf16x8*)(qg + (size_t)ncB*32 + g*8);
    const int cnA = MIXED ? cnt[ncA] : 0;
    const int cnB = MIXED ? cnt[ncB] : 0;
    const float* browA = bias_h + (size_t)ncA*392;
    const float* browB = bias_h + (size_t)ncB*392;
    f32x4 o0a = {0.f,0.f,0.f,0.f}, o1a = o0a, o2a = o0a;
    f32x4 o0b = o0a, o1b = o0a, o2b = o0a;
    // software pipeline: slot0 holds jt=2mc, slot1 holds jt=2mc+1; prefetch 1 ahead
    bf16x8 kf0 = ldK(klds, 0, c, g);
    float4 ba0 = ldB(browA, 0, g), bb0 = ldB(browB, 0, g);
    int4   cm0 = MIXED ? ldC(cnt, 0, g) : zc;
    for (int mc = 0; mc < 12; ++mc){
      const int jt1 = 2*mc + 1, jt2 = 2*mc + 2;
      bf16x8 kf1 = ldK(klds, jt1, c, g);
      float4 ba1 = ldB(browA, jt1, g), bb1 = ldB(browB, jt1, g);
      int4   cm1 = MIXED ? ldC(cnt, jt1, g) : zc;
      QKT_BODY(0, false, kf0, ba0, bb0, cm0, 2*mc);
      kf0 = ldK(klds, jt2, c, g);
      ba0 = ldB(browA, jt2, g); bb0 = ldB(browB, jt2, g);
      cm0 = MIXED ? ldC(cnt, jt2, g) : zc;
      QKT_BODY(1, false, kf1, ba1, bb1, cm1, jt1);
      PV_PAIR(mc);
    }
    QKT_BODY(0, true, kf0, ba0, bb0, cm0, 24);   // jt = 24 (prefetched at mc=11)
    { uint2 zz; zz.x = 0u; zz.y = 0u;
      *(uint2*)&psA[c*20 + 8 + 2*g] = zz;
      *(uint2*)&psB[c*20 + 8 + 2*g] = zz; }
    PV_PAIR(12);
    // normalize + coalesced store via LDS bounce
    const float rva = 1.f / o2a[0];
    const float rvb = 1.f / o2b[0];
    uint2 wa, wb2;
    wa.x  = cvtpk(o0a[0]*rva, o0a[1]*rva);  wa.y  = cvtpk(o0a[2]*rva, o0a[3]*rva);
    wb2.x = cvtpk(o1a[0]*rva, o1a[1]*rva);  wb2.y = cvtpk(o1a[2]*rva, o1a[3]*rva);
    *(uint2*)&psA[c*20 + 2*g]     = wa;
    *(uint2*)&psA[c*20 + 8 + 2*g] = wb2;
    wa.x  = cvtpk(o0b[0]*rvb, o0b[1]*rvb);  wa.y  = cvtpk(o0b[2]*rvb, o0b[3]*rvb);
    wb2.x = cvtpk(o1b[0]*rvb, o1b[1]*rvb);  wb2.y = cvtpk(o1b[2]*rvb, o1b[3]*rvb);
    *(uint2*)&psB[c*20 + 2*g]     = wa;
    *(uint2*)&psB[c*20 + 8 + 2*g] = wb2;
    const int orow = lane>>2, oq = lane&3;
    uint4 ova = *(const uint4*)&psA[orow*20 + 4*oq];
    const int nA = nbA + orow;
    if (nA < 392)
      *(uint4*)(aout + ((size_t)(win*392 + nA))*128 + h*32 + oq*8) = ova;
    if (hasB){
      uint4 ovb = *(const uint4*)&psB[orow*20 + 4*oq];
      const int nB = nbB + orow;
      if (nB < 392)
        *(uint4*)(aout + ((size_t)(win*392 + nB))*128 + h*32 + oq*8) = ovb;
    }
  }
}

__global__ __launch_bounds__(512,4) void k_attn(const u16* __restrict__ qkv,
    const float* __restrict__ bias16, u16* __restrict__ aout){
  __shared__ __align__(16) u16 klds[400*40];   // K-hat rows [m][k] (32000 B)
  __shared__ __align__(16) u16 vT[32*424];     // V^T [ch][m] (27136 B)
  __shared__ __align__(16) u32 ps[8][640];     // per-wave P/O scratch x2 (20480 B)
  __shared__ __align__(16) int cnt[400];       // region ids (1600 B)
  const int tid = threadIdx.x;
  const int win = blockIdx.x, h = blockIdx.y;
  const int dwi = win>>6, hwi = (win>>3)&7, wwi = win&7;
  const u16* qg = qkv + ((size_t)(0*4 + h)*NTOK + (size_t)win*392)*32;
  const u16* kg = qkv + ((size_t)(1*4 + h)*NTOK + (size_t)win*392)*32;
  const u16* vg = qkv + ((size_t)(2*4 + h)*NTOK + (size_t)win*392)*32;
  // ---- stage K-hat rows (plain copy, zeros for rows >= 392)
  for (int idx = tid; idx < 1600; idx += 512){
    const int row = idx>>2, q = idx&3;
    uint4 a = {0,0,0,0};
    if (row < 392) a = *(const uint4*)(kg + (size_t)row*32 + q*8);
    *(uint4*)&klds[row*40 + q*8] = a;
  }
  // ---- stage V transposed: 4-row register repack (b64 writes along m)
  for (int idx = tid; idx < 784; idx += 512){
    const int mg = idx>>3, cg = idx&7;
    uint2 v0 = *(const uint2*)(vg + (size_t)(4*mg+0)*32 + cg*4);
    uint2 v1 = *(const uint2*)(vg + (size_t)(4*mg+1)*32 + cg*4);
    uint2 v2 = *(const uint2*)(vg + (size_t)(4*mg+2)*32 + cg*4);
    uint2 v3 = *(const uint2*)(vg + (size_t)(4*mg+3)*32 + cg*4);
    u16 e0[4], e1[4], e2[4], e3[4];
    e0[0]=(u16)v0.x; e0[1]=(u16)(v0.x>>16); e0[2]=(u16)v0.y; e0[3]=(u16)(v0.y>>16);
    e1[0]=(u16)v1.x; e1[1]=(u16)(v1.x>>16); e1[2]=(u16)v1.y; e1[3]=(u16)(v1.y>>16);
    e2[0]=(u16)v2.x; e2[1]=(u16)(v2.x>>16); e2[2]=(u16)v2.y; e2[3]=(u16)(v2.y>>16);
    e3[0]=(u16)v3.x; e3[1]=(u16)(v3.x>>16); e3[2]=(u16)v3.y; e3[3]=(u16)(v3.y>>16);
    #pragma unroll
    for (int cc=0; cc<4; ++cc){
      ushort4 w = make_ushort4(e0[cc], e1[cc], e2[cc], e3[cc]);
      *(ushort4*)&vT[(cg*4+cc)*424 + 4*mg] = w;
    }
  }
  for (int idx = tid; idx < 1024; idx += 512){
    int ch = idx>>5, mm = 392 + (idx&31);
    vT[ch*424 + mm] = 0;
  }
  // ---- region ids
  for (int t2 = tid; t2 < 400; t2 += 512){
    int row = (t2 < 392) ? t2 : 391;
    int td = row/49; int r2 = row - td*49; int th = r2/7; int tw = r2 - th*7;
    int gd = dwi*8 + td, gh = hwi*7 + th, gw = wwi*7 + tw;
    int rd = (gd < 8) ? 0 : ((gd < 12) ? 1 : 2);
    int rh = (gh < 49) ? 0 : ((gh < 53) ? 1 : 2);
    int rw = (gw < 49) ? 0 : ((gw < 53) ? 1 : 2);
    cnt[t2] = rd*9 + rh*3 + rw;
  }
  __syncthreads();
  const int wave = tid>>6, lane = tid&63;
  u32* psA = &ps[wave][0];
  u32* psB = &ps[wave][320];
  const float* bias_h = bias16 + (size_t)h*153664;
  const bool uniform = (dwi == 0) && (hwi < 7) && (wwi < 7);
  if (uniform)
    attn_main<false>(qg, bias_h, klds, vT, psA, psB, cnt, aout, win, h, wave, lane);
  else
    attn_main<true >(qg, bias_h, klds, vT, psA, psB, cnt, aout, win, h, wave, lane);
}

// ---------------- 5) projection GEMM via MFMA + window reverse + roll-back
__global__ __launch_bounds__(256,2) void k_proj(const u16* __restrict__ ain,
    const u16* __restrict__ wb, const void* __restrict__ x, void* __restrict__ out){
  __shared__ __align__(16) u16 As[64*136];
  __shared__ __align__(16) u16 Ws[128*136];
  const int tid = threadIdx.x;
  const int lane = tid & 63;
  const int isf32 = detect_f32(x, lane);
  const int tokbase0 = blockIdx.x*64;
  {
    int trow = tid>>2, cq = (tid&3)*32;
    const uint4* src = (const uint4*)(ain + (size_t)(tokbase0+trow)*128 + cq);
    #pragma unroll
    for (int u=0; u<4; ++u) *(uint4*)&As[trow*136 + cq + u*8] = src[u];
  }
  {
    int orow = tid>>1, c2 = (tid&1)*64;
    const uint4* src = (const uint4*)(wb + WB_PW + (size_t)orow*128 + c2);
    #pragma unroll
    for (int u=0; u<8; ++u) *(uint4*)&Ws[orow*136 + c2 + u*8] = src[u];
  }
  __syncthreads();
  const int wave = tid>>6;
  const int c = lane & 15, g = lane >> 4;
  bf16x8 ka[4];
  #pragma unroll
  for (int kk=0; kk<4; ++kk)
    ka[kk] = *(const bf16x8*)&As[(wave*16 + c)*136 + kk*32 + g*8];
  f32x4 acc[8];
  #pragma unroll
  for (int nt=0; nt<8; ++nt) acc[nt] = 0.f;
  #pragma unroll
  for (int nt=0; nt<8; ++nt){
    #pragma unroll
    for (int kk=0; kk<4; ++kk){
      bf16x8 wf = *(const bf16x8*)&Ws[(nt*16 + c)*136 + kk*32 + g*8];
      acc[nt] = mfma16(ka[kk], wf, acc[nt]);
    }
  }
  if (isf32){
    __syncthreads();
    float* WsF = (float*)Ws;
    #pragma unroll
    for (int nt=0; nt<8; ++nt){
      float bv = b2f(wb[WB_PB + nt*16 + c]);
      #pragma unroll
      for (int r=0;r<4;++r)
        WsF[(wave*16 + 4*g + r)*128 + nt*16 + c] = acc[nt][r] + bv;
    }
    __syncthreads();
    const int tok = tid>>2, q4 = tid&3;
    int gtok = tokbase0 + tok;
    int win = gtok/392, tt = gtok - win*392;
    int dwi = win>>6, hwi = (win>>3)&7, wwi = win&7;
    int td = tt/49; int r2 = tt - td*49; int th = r2/7; int tw = r2 - th*7;
    int pd = dwi*8 + td + 4; if (pd >= 16) pd -= 16;
    int ph = hwi*7 + th + 3; if (ph >= 56) ph -= 56;
    int pwx = wwi*7 + tw + 3; if (pwx >= 56) pwx -= 56;
    size_t po = (size_t)((pd*56 + ph)*56 + pwx)*128;
    const float4* srcv = (const float4*)&WsF[tok*128 + q4*32];
    float4* dst = (float4*)((float*)out + po + q4*32);
    #pragma unroll
    for (int i=0;i<8;++i) dst[i] = srcv[i];
  } else {
    const int tokbase = tokbase0 + wave*16;
    size_t po[4];
    #pragma unroll
    for (int r=0;r<4;++r){
      int gtok = tokbase + 4*g + r;
      int win = gtok/392, tt = gtok - win*392;
      int dwi = win>>6, hwi = (win>>3)&7, wwi = win&7;
      int td = tt/49; int r2 = tt - td*49; int th = r2/7; int tw = r2 - th*7;
      int pd = dwi*8 + td + 4; if (pd >= 16) pd -= 16;
      int ph = hwi*7 + th + 3; if (ph >= 56) ph -= 56;
      int pwx = wwi*7 + tw + 3; if (pwx >= 56) pwx -= 56;
      po[r] = (size_t)((pd*56 + ph)*56 + pwx)*128;
    }
    #pragma unroll
    for (int nt=0; nt<8; ++nt){
      int oc = nt*16 + c;
      float bv = b2f(wb[WB_PB + oc]);
      #pragma unroll
      for (int r=0;r<4;++r)
        ((u16*)out)[po[r] + oc] = f2b(acc[nt][r] + bv);
    }
  }
}

extern "C" void kernel_launch(void* const* d_in, const int* in_sizes, int n_in,
                              void* d_out, int out_size, void* d_ws, size_t ws_size,
                              hipStream_t stream){
  const void* x      = d_in[0];
  const void* qkv_w  = d_in[1];
  const void* qkv_b  = d_in[2];
  const void* proj_w = d_in[3];
  const void* proj_b = d_in[4];
  const void* lsc    = d_in[5];
  const void* cpb_w1 = d_in[6];
  const void* cpb_b1 = d_in[7];
  const void* cpb_w2 = d_in[8];
  char* ws = (char*)d_ws;
  float* table16 = (float*)(ws);                     // 40,960 B
  float* bias16  = (float*)(ws + 40960);             // 2,458,624 B
  u16*   wb      = (u16*)(ws + 2499584);             // 132,096 B
  u16*   qkvbuf  = (u16*)(ws + 2631680);             // 38,535,168 B
  u16*   attnout = (u16*)(ws + 41166848);            // 12,845,056 B

  k_cpb <<<TBL, 64, 0, stream>>>(cpb_w1, cpb_b1, cpb_w2, x,
                                 qkv_w, proj_w, qkv_b, proj_b, wb, table16);
  k_bias<<<dim3(392,4), 128, 0, stream>>>(table16, bias16);
  k_qkv <<<784, 256, 0, stream>>>(x, wb, lsc, qkvbuf);
  k_attn<<<dim3(128,4), 512, 0, stream>>>(qkvbuf, bias16, attnout);
  k_proj<<<784, 256, 0, stream>>>(attnout, wb, x, d_out);
}

// Round 11
// 94.891 us; speedup vs baseline: 1.1115x; 1.1115x over previous
//
#include <hip/hip_runtime.h>
#include <hip/hip_bf16.h>

typedef unsigned short u16;
typedef unsigned int   u32;
typedef float f32x4  __attribute__((ext_vector_type(4)));
typedef short bf16x8 __attribute__((ext_vector_type(8)));

#define DI __device__ __forceinline__

constexpr int TBL  = 2535;     // (2*8-1)*(2*7-1)*(2*7-1)
constexpr int NTOK = 50176;    // 128 windows * 392 tokens
constexpr float L2E = 1.4426950408889634f;

// bf16 weight scratch layout (u16 units)
constexpr int WB_QW = 0;          // 49152
constexpr int WB_PW = 49152;      // 16384
constexpr int WB_QB = 65536;      // 384
constexpr int WB_PB = 65920;      // 128
constexpr int WB_TOT = 66048;

DI float b2f(u16 u){ return __uint_as_float(((u32)u)<<16); }
DI u16 f2b(float f){
  u32 u = __float_as_uint(f);
  return (u16)((u + 0x7fffu + ((u>>16)&1u)) >> 16);
}
DI float ldf(const void* p, int i, int isf32){
  return isf32 ? ((const float*)p)[i] : b2f(((const u16*)p)[i]);
}
DI f32x4 mfma32(bf16x8 a, bf16x8 b, f32x4 c){
  return __builtin_amdgcn_mfma_f32_16x16x32_bf16(a, b, c, 0, 0, 0);
}
DI u32 cvtpk(float lo, float hi){
  u32 r;
  asm("v_cvt_pk_bf16_f32 %0, %1, %2" : "=v"(r) : "v"(lo), "v"(hi));
  return r;
}
DI float vexp2(float x){
  float r;
  asm("v_exp_f32 %0, %1" : "=v"(r) : "v"(x));
  return r;
}
// per-wave dtype self-detect: low u16 of 64 words of x viewed as bf16.
DI int detect_f32(const void* x, int lane){
  u32 w = ((const u32*)x)[lane];
  u16 lo = (u16)w;
  u32 e = (lo >> 7) & 0xFF;
  int wild = (lo != 0 && (e >= 143 || e <= 111)) ? 1 : 0;
  unsigned long long m = __ballot(wild);
  return __popcll(m) > 16;
}

// ---------------- 1) CPB MLP table (value = (16*sigmoid - 15) * log2(e))
__global__ void k_cpb(const void* __restrict__ w1, const void* __restrict__ b1,
                      const void* __restrict__ w2, const void* __restrict__ x,
                      const void* __restrict__ qw, const void* __restrict__ pw,
                      const void* __restrict__ qb, const void* __restrict__ pb,
                      u16* __restrict__ wb, float* __restrict__ table16){
  const int lane = threadIdx.x;
  const int isf32 = detect_f32(x, lane);
  { // merged weight conversion
    int gid = blockIdx.x*64 + lane;
    if (gid < WB_TOT){
      const void* src; int off;
      if (gid < WB_PW)      { src = qw; off = gid; }
      else if (gid < WB_QB) { src = pw; off = gid - WB_PW; }
      else if (gid < WB_PB) { src = qb; off = gid - WB_QB; }
      else                  { src = pb; off = gid - WB_PB; }
      wb[gid] = isf32 ? f2b(((const float*)src)[off]) : ((const u16*)src)[off];
    }
  }
  int t = blockIdx.x;
  int i = t/169; int r = t - i*169; int j = r/13; int k = r - j*13;
  float v0 = 8.f*(float)(i-7)/7.f, v1 = 8.f*(float)(j-6)/6.f, v2 = 8.f*(float)(k-6)/6.f;
  float c0 = copysignf(log2f(fabsf(v0)+1.f)*(1.f/3.f), v0);
  float c1 = copysignf(log2f(fabsf(v1)+1.f)*(1.f/3.f), v1);
  float c2 = copysignf(log2f(fabsf(v2)+1.f)*(1.f/3.f), v2);
  float a0=0.f,a1=0.f,a2=0.f,a3=0.f;
  for (int hh = lane; hh < 512; hh += 64){
    float a = c0*ldf(w1,hh*3,isf32) + c1*ldf(w1,hh*3+1,isf32)
            + c2*ldf(w1,hh*3+2,isf32) + ldf(b1,hh,isf32);
    a = fmaxf(a, 0.f);
    a0 += a*ldf(w2,hh,isf32);       a1 += a*ldf(w2,512+hh,isf32);
    a2 += a*ldf(w2,1024+hh,isf32);  a3 += a*ldf(w2,1536+hh,isf32);
  }
  #pragma unroll
  for (int off=32; off; off>>=1){
    a0 += __shfl_xor(a0, off); a1 += __shfl_xor(a1, off);
    a2 += __shfl_xor(a2, off); a3 += __shfl_xor(a3, off);
  }
  if (lane==0){
    table16[t]       = (16.f/(1.f+__expf(-a0)) - 15.f)*L2E;
    table16[TBL+t]   = (16.f/(1.f+__expf(-a1)) - 15.f)*L2E;
    table16[2*TBL+t] = (16.f/(1.f+__expf(-a2)) - 15.f)*L2E;
    table16[3*TBL+t] = (16.f/(1.f+__expf(-a3)) - 15.f)*L2E;
  }
}

// ---------------- 2) expand to bias16[h][n][m] (f32, pre-scaled by log2e)
__global__ void k_bias(const float* __restrict__ table16, float* __restrict__ bias16){
  int n = blockIdx.x, h = blockIdx.y;
  int td = n/49; int r2 = n - td*49; int th = r2/7; int tw = r2 - th*7;
  const float* tb = table16 + h*TBL;
  float* o = bias16 + ((size_t)h*392 + n)*392;
  for (int m = threadIdx.x; m < 392; m += 128){
    int sd = m/49; int q2 = m - sd*49; int sh = q2/7; int sw = q2 - sh*7;
    int idx = (td - sd + 7)*169 + (th - sh + 6)*13 + (tw - sw + 6);
    o[m] = tb[idx];
  }
}

// ---------------- 3) QKV GEMM via MFMA: A-fragments direct from global,
//                    LDS only for weights, fused Q/K row-normalization
__global__ __launch_bounds__(256,4) void k_qkv(const void* __restrict__ x,
    const u16* __restrict__ wb, const void* __restrict__ lsc,
    u16* __restrict__ qkvbuf){
  __shared__ __align__(16) u16 Ws[128*136];  // [oc][k] only (34,816 B)
  const int tid = threadIdx.x;
  const int lane = tid & 63;
  const int isf32 = detect_f32(x, lane);
  const int wave = tid>>6;
  const int c = lane & 15, g = lane >> 4;
  const int tokbase = blockIdx.x*64 + wave*16;
  // A-fragment: token row (c), k-cols kk*32 + g*8 .. +7, straight from global
  bf16x8 ka[4];
  {
    int gtok = tokbase + c;
    int win = gtok/392, tt = gtok - win*392;
    int dwi = win>>6, hwi = (win>>3)&7, wwi = win&7;
    int td = tt/49; int r2 = tt - td*49; int th = r2/7; int tw = r2 - th*7;
    int pd = dwi*8 + td + 4; if (pd >= 16) pd -= 16;
    int ph = hwi*7 + th + 3; if (ph >= 56) ph -= 56;
    int pw = wwi*7 + tw + 3; if (pw >= 56) pw -= 56;
    size_t rowb = (size_t)((pd*56 + ph)*56 + pw)*128;
    if (isf32){
      const float* xr = (const float*)x + rowb + g*8;
      #pragma unroll
      for (int kk=0; kk<4; ++kk){
        float4 f0 = *(const float4*)(xr + kk*32);
        float4 f1 = *(const float4*)(xr + kk*32 + 4);
        uint4 p;
        p.x = cvtpk(f0.x, f0.y);  p.y = cvtpk(f0.z, f0.w);
        p.z = cvtpk(f1.x, f1.y);  p.w = cvtpk(f1.z, f1.w);
        ka[kk] = *(bf16x8*)&p;
      }
    } else {
      const u16* xr = (const u16*)x + rowb + g*8;
      #pragma unroll
      for (int kk=0; kk<4; ++kk)
        ka[kk] = *(const bf16x8*)(xr + kk*32);
    }
  }
  // per-head scale*log2e
  float sl2e[4];
  #pragma unroll
  for (int h2=0; h2<4; ++h2){
    float ls = ldf(lsc, h2, isf32);
    sl2e[h2] = __expf(fminf(ls, 4.60517019f)) * L2E;
  }
  for (int which = 0; which < 3; ++which){
    if (which) __syncthreads();   // prev Ws reads done
    { // stage weight rows [which*128 .. +127] (bf16 preconverted)
      int orow = tid>>1, c2 = (tid&1)*64;
      const uint4* src = (const uint4*)(wb + WB_QW + (size_t)(which*128 + orow)*128 + c2);
      #pragma unroll
      for (int u=0; u<8; ++u) *(uint4*)&Ws[orow*136 + c2 + u*8] = src[u];
    }
    __syncthreads();   // Ws ready
    f32x4 acc[8];
    #pragma unroll
    for (int nt=0; nt<8; ++nt) acc[nt] = 0.f;
    #pragma unroll
    for (int nt=0; nt<8; ++nt){
      #pragma unroll
      for (int kk=0; kk<4; ++kk){
        bf16x8 wf = *(const bf16x8*)&Ws[(nt*16 + c)*136 + kk*32 + g*8];
        acc[nt] = mfma32(ka[kk], wf, acc[nt]);
      }
    }
    // add bias (k-bias zeroed per Swin v2)
    if (which != 1){
      #pragma unroll
      for (int nt=0; nt<8; ++nt){
        float bv = b2f(wb[WB_QB + which*128 + nt*16 + c]);
        #pragma unroll
        for (int r=0;r<4;++r) acc[nt][r] += bv;
      }
    }
    // row-normalize q/k per head (reduce over the 16 c-lanes)
    if (which < 2){
      #pragma unroll
      for (int h2=0; h2<4; ++h2){
        f32x4 ss;
        #pragma unroll
        for (int r=0;r<4;++r)
          ss[r] = acc[2*h2][r]*acc[2*h2][r] + acc[2*h2+1][r]*acc[2*h2+1][r];
        #pragma unroll
        for (int off=1; off<16; off<<=1){
          #pragma unroll
          for (int r=0;r<4;++r) ss[r] += __shfl_xor(ss[r], off);
        }
        #pragma unroll
        for (int r=0;r<4;++r){
          float rn = rsqrtf(fmaxf(ss[r], 1e-24f));
          if (which == 0) rn *= sl2e[h2];
          acc[2*h2][r]   *= rn;
          acc[2*h2+1][r] *= rn;
        }
      }
    }
    #pragma unroll
    for (int nt=0; nt<8; ++nt){
      int oc = nt*16 + c;
      int head = oc >> 5, chb = oc & 31;
      #pragma unroll
      for (int r=0;r<4;++r){
        int t = tokbase + 4*g + r;
        qkvbuf[((size_t)(which*4+head)*NTOK + t)*32 + chb] = f2b(acc[nt][r]);
      }
    }
  }
}

// ---------------- 4) attention: paired Q-tiles + 1-step K/bias prefetch pipeline
//                    (round-9-green version: LDS P round-trip, K=32 PV, ones-MFMA sum)
DI bf16x8 ldK(const u16* klds, int jt, int c, int g){
  return *(const bf16x8*)&klds[(jt*16 + c)*40 + g*8];
}
DI float4 ldB(const float* brow, int jt, int g){
  int mbc = jt*16 + 4*g; if (mbc > 388) mbc = 388;
  return *(const float4*)(brow + mbc);
}
DI int4 ldC(const int* cnt, int jt, int g){
  int mbc = jt*16 + 4*g; if (mbc > 388) mbc = 388;
  return *(const int4*)&cnt[mbc];
}

#define QKT_BODY(JJ, TAIL, KF, BA, BB, CM, JT) do { \
  f32x4 tz = {0.f,0.f,0.f,0.f}; \
  f32x4 ta = mfma32(KF, qfa, tz); \
  f32x4 tb = mfma32(KF, qfb, tz); \
  float pa0 = vexp2(ta[0] + BA.x), pa1 = vexp2(ta[1] + BA.y); \
  float pa2 = vexp2(ta[2] + BA.z), pa3 = vexp2(ta[3] + BA.w); \
  float pb0 = vexp2(tb[0] + BB.x), pb1 = vexp2(tb[1] + BB.y); \
  float pb2 = vexp2(tb[2] + BB.z), pb3 = vexp2(tb[3] + BB.w); \
  if (MIXED){ \
    if (CM.x != cnA) pa0 = 0.f;  if (CM.y != cnA) pa1 = 0.f; \
    if (CM.z != cnA) pa2 = 0.f;  if (CM.w != cnA) pa3 = 0.f; \
    if (CM.x != cnB) pb0 = 0.f;  if (CM.y != cnB) pb1 = 0.f; \
    if (CM.z != cnB) pb2 = 0.f;  if (CM.w != cnB) pb3 = 0.f; \
  } \
  if (TAIL){ \
    const int mb = (JT)*16 + 4*g; \
    if (mb > 388){ pa0=0.f; pa1=0.f; pa2=0.f; pa3=0.f; \
                   pb0=0.f; pb1=0.f; pb2=0.f; pb3=0.f; } \
  } \
  uint2 wva, wvb; \
  wva.x = cvtpk(pa0,pa1); wva.y = cvtpk(pa2,pa3); \
  wvb.x = cvtpk(pb0,pb1); wvb.y = cvtpk(pb2,pb3); \
  *(uint2*)&psA[c*20 + (JJ)*8 + 2*g] = wva; \
  *(uint2*)&psB[c*20 + (JJ)*8 + 2*g] = wvb; \
} while(0)

#define PV_PAIR(MC) do { \
  bf16x8 pfa = *(const bf16x8*)&psA[c*20 + 4*g]; \
  bf16x8 pfb = *(const bf16x8*)&psB[c*20 + 4*g]; \
  bf16x8 va = *(const bf16x8*)&vT[c*424 + (MC)*32 + g*8]; \
  bf16x8 vb = *(const bf16x8*)&vT[(16+c)*424 + (MC)*32 + g*8]; \
  o0a = mfma32(va, pfa, o0a); o1a = mfma32(vb, pfa, o1a); o2a = mfma32(ones, pfa, o2a); \
  o0b = mfma32(va, pfb, o0b); o1b = mfma32(vb, pfb, o1b); o2b = mfma32(ones, pfb, o2b); \
} while(0)

template<bool MIXED>
DI void attn_main(const u16* __restrict__ qg, const float* __restrict__ bias_h,
                  const u16* klds, const u16* vT, u32* psA, u32* psB, const int* cnt,
                  u16* __restrict__ aout, int win, int h, int wave, int lane){
  const int c = lane & 15, g = lane >> 4;
  const short ob = 0x3F80;
  const bf16x8 ones = {ob,ob,ob,ob,ob,ob,ob,ob};
  const int4 zc = {0,0,0,0};
  for (int pp = wave; pp < 13; pp += 8){
    const int rta = 2*pp;
    const int rtb = (pp < 12) ? (2*pp+1) : 24;
    const bool hasB = (pp < 12);
    const int nbA = rta*16, nbB = rtb*16;
    const int ncA = (nbA + c < 392) ? (nbA + c) : 391;
    const int ncB = (nbB + c < 392) ? (nbB + c) : 391;
    const bf16x8 qfa = *(const bf16x8*)(qg + (size_t)ncA*32 + g*8);
    const bf16x8 qfb = *(const bf16x8*)(qg + (size_t)ncB*32 + g*8);
    const int cnA = MIXED ? cnt[ncA] : 0;
    const int cnB = MIXED ? cnt[ncB] : 0;
    const float* browA = bias_h + (size_t)ncA*392;
    const float* browB = bias_h + (size_t)ncB*392;
    f32x4 o0a = {0.f,0.f,0.f,0.f}, o1a = o0a, o2a = o0a;
    f32x4 o0b = o0a, o1b = o0a, o2b = o0a;
    // software pipeline: slot0 holds jt=2mc, slot1 holds jt=2mc+1; prefetch 1 ahead
    bf16x8 kf0 = ldK(klds, 0, c, g);
    float4 ba0 = ldB(browA, 0, g), bb0 = ldB(browB, 0, g);
    int4   cm0 = MIXED ? ldC(cnt, 0, g) : zc;
    for (int mc = 0; mc < 12; ++mc){
      const int jt1 = 2*mc + 1, jt2 = 2*mc + 2;
      bf16x8 kf1 = ldK(klds, jt1, c, g);
      float4 ba1 = ldB(browA, jt1, g), bb1 = ldB(browB, jt1, g);
      int4   cm1 = MIXED ? ldC(cnt, jt1, g) : zc;
      QKT_BODY(0, false, kf0, ba0, bb0, cm0, 2*mc);
      kf0 = ldK(klds, jt2, c, g);
      ba0 = ldB(browA, jt2, g); bb0 = ldB(browB, jt2, g);
      cm0 = MIXED ? ldC(cnt, jt2, g) : zc;
      QKT_BODY(1, false, kf1, ba1, bb1, cm1, jt1);
      PV_PAIR(mc);
    }
    QKT_BODY(0, true, kf0, ba0, bb0, cm0, 24);   // jt = 24 (prefetched at mc=11)
    { uint2 zz; zz.x = 0u; zz.y = 0u;
      *(uint2*)&psA[c*20 + 8 + 2*g] = zz;
      *(uint2*)&psB[c*20 + 8 + 2*g] = zz; }
    PV_PAIR(12);
    // normalize + coalesced store via LDS bounce
    const float rva = 1.f / o2a[0];
    const float rvb = 1.f / o2b[0];
    uint2 wa, wb2;
    wa.x  = cvtpk(o0a[0]*rva, o0a[1]*rva);  wa.y  = cvtpk(o0a[2]*rva, o0a[3]*rva);
    wb2.x = cvtpk(o1a[0]*rva, o1a[1]*rva);  wb2.y = cvtpk(o1a[2]*rva, o1a[3]*rva);
    *(uint2*)&psA[c*20 + 2*g]     = wa;
    *(uint2*)&psA[c*20 + 8 + 2*g] = wb2;
    wa.x  = cvtpk(o0b[0]*rvb, o0b[1]*rvb);  wa.y  = cvtpk(o0b[2]*rvb, o0b[3]*rvb);
    wb2.x = cvtpk(o1b[0]*rvb, o1b[1]*rvb);  wb2.y = cvtpk(o1b[2]*rvb, o1b[3]*rvb);
    *(uint2*)&psB[c*20 + 2*g]     = wa;
    *(uint2*)&psB[c*20 + 8 + 2*g] = wb2;
    const int orow = lane>>2, oq = lane&3;
    uint4 ova = *(const uint4*)&psA[orow*20 + 4*oq];
    const int nA = nbA + orow;
    if (nA < 392)
      *(uint4*)(aout + ((size_t)(win*392 + nA))*128 + h*32 + oq*8) = ova;
    if (hasB){
      uint4 ovb = *(const uint4*)&psB[orow*20 + 4*oq];
      const int nB = nbB + orow;
      if (nB < 392)
        *(uint4*)(aout + ((size_t)(win*392 + nB))*128 + h*32 + oq*8) = ovb;
    }
  }
}

__global__ __launch_bounds__(512,4) void k_attn(const u16* __restrict__ qkv,
    const float* __restrict__ bias16, u16* __restrict__ aout){
  __shared__ __align__(16) u16 klds[400*40];   // K-hat rows [m][k] (32000 B)
  __shared__ __align__(16) u16 vT[32*424];     // V^T [ch][m] (27136 B)
  __shared__ __align__(16) u32 ps[8][640];     // per-wave P/O scratch x2 (20480 B)
  __shared__ __align__(16) int cnt[400];       // region ids (1600 B)
  const int tid = threadIdx.x;
  const int win = blockIdx.x, h = blockIdx.y;
  const int dwi = win>>6, hwi = (win>>3)&7, wwi = win&7;
  const u16* qg = qkv + ((size_t)(0*4 + h)*NTOK + (size_t)win*392)*32;
  const u16* kg = qkv + ((size_t)(1*4 + h)*NTOK + (size_t)win*392)*32;
  const u16* vg = qkv + ((size_t)(2*4 + h)*NTOK + (size_t)win*392)*32;
  // ---- stage K-hat rows (plain copy, zeros for rows >= 392)
  for (int idx = tid; idx < 1600; idx += 512){
    const int row = idx>>2, q = idx&3;
    uint4 a = {0,0,0,0};
    if (row < 392) a = *(const uint4*)(kg + (size_t)row*32 + q*8);
    *(uint4*)&klds[row*40 + q*8] = a;
  }
  // ---- stage V transposed: 4-row register repack (b64 writes along m)
  for (int idx = tid; idx < 784; idx += 512){
    const int mg = idx>>3, cg = idx&7;
    uint2 v0 = *(const uint2*)(vg + (size_t)(4*mg+0)*32 + cg*4);
    uint2 v1 = *(const uint2*)(vg + (size_t)(4*mg+1)*32 + cg*4);
    uint2 v2 = *(const uint2*)(vg + (size_t)(4*mg+2)*32 + cg*4);
    uint2 v3 = *(const uint2*)(vg + (size_t)(4*mg+3)*32 + cg*4);
    u16 e0[4], e1[4], e2[4], e3[4];
    e0[0]=(u16)v0.x; e0[1]=(u16)(v0.x>>16); e0[2]=(u16)v0.y; e0[3]=(u16)(v0.y>>16);
    e1[0]=(u16)v1.x; e1[1]=(u16)(v1.x>>16); e1[2]=(u16)v1.y; e1[3]=(u16)(v1.y>>16);
    e2[0]=(u16)v2.x; e2[1]=(u16)(v2.x>>16); e2[2]=(u16)v2.y; e2[3]=(u16)(v2.y>>16);
    e3[0]=(u16)v3.x; e3[1]=(u16)(v3.x>>16); e3[2]=(u16)v3.y; e3[3]=(u16)(v3.y>>16);
    #pragma unroll
    for (int cc=0; cc<4; ++cc){
      ushort4 w = make_ushort4(e0[cc], e1[cc], e2[cc], e3[cc]);
      *(ushort4*)&vT[(cg*4+cc)*424 + 4*mg] = w;
    }
  }
  for (int idx = tid; idx < 1024; idx += 512){
    int ch = idx>>5, mm = 392 + (idx&31);
    vT[ch*424 + mm] = 0;
  }
  // ---- region ids
  for (int t2 = tid; t2 < 400; t2 += 512){
    int row = (t2 < 392) ? t2 : 391;
    int td = row/49; int r2 = row - td*49; int th = r2/7; int tw = r2 - th*7;
    int gd = dwi*8 + td, gh = hwi*7 + th, gw = wwi*7 + tw;
    int rd = (gd < 8) ? 0 : ((gd < 12) ? 1 : 2);
    int rh = (gh < 49) ? 0 : ((gh < 53) ? 1 : 2);
    int rw = (gw < 49) ? 0 : ((gw < 53) ? 1 : 2);
    cnt[t2] = rd*9 + rh*3 + rw;
  }
  __syncthreads();
  const int wave = tid>>6, lane = tid&63;
  u32* psA = &ps[wave][0];
  u32* psB = &ps[wave][320];
  const float* bias_h = bias16 + (size_t)h*153664;
  const bool uniform = (dwi == 0) && (hwi < 7) && (wwi < 7);
  if (uniform)
    attn_main<false>(qg, bias_h, klds, vT, psA, psB, cnt, aout, win, h, wave, lane);
  else
    attn_main<true >(qg, bias_h, klds, vT, psA, psB, cnt, aout, win, h, wave, lane);
}

// ---------------- 5) projection GEMM via MFMA + window reverse + roll-back
__global__ __launch_bounds__(256,2) void k_proj(const u16* __restrict__ ain,
    const u16* __restrict__ wb, const void* __restrict__ x, void* __restrict__ out){
  __shared__ __align__(16) u16 As[64*136];
  __shared__ __align__(16) u16 Ws[128*136];
  const int tid = threadIdx.x;
  const int lane = tid & 63;
  const int isf32 = detect_f32(x, lane);
  const int tokbase0 = blockIdx.x*64;
  {
    int trow = tid>>2, cq = (tid&3)*32;
    const uint4* src = (const uint4*)(ain + (size_t)(tokbase0+trow)*128 + cq);
    #pragma unroll
    for (int u=0; u<4; ++u) *(uint4*)&As[trow*136 + cq + u*8] = src[u];
  }
  {
    int orow = tid>>1, c2 = (tid&1)*64;
    const uint4* src = (const uint4*)(wb + WB_PW + (size_t)orow*128 + c2);
    #pragma unroll
    for (int u=0; u<8; ++u) *(uint4*)&Ws[orow*136 + c2 + u*8] = src[u];
  }
  __syncthreads();
  const int wave = tid>>6;
  const int c = lane & 15, g = lane >> 4;
  bf16x8 ka[4];
  #pragma unroll
  for (int kk=0; kk<4; ++kk)
    ka[kk] = *(const bf16x8*)&As[(wave*16 + c)*136 + kk*32 + g*8];
  f32x4 acc[8];
  #pragma unroll
  for (int nt=0; nt<8; ++nt) acc[nt] = 0.f;
  #pragma unroll
  for (int nt=0; nt<8; ++nt){
    #pragma unroll
    for (int kk=0; kk<4; ++kk){
      bf16x8 wf = *(const bf16x8*)&Ws[(nt*16 + c)*136 + kk*32 + g*8];
      acc[nt] = mfma32(ka[kk], wf, acc[nt]);
    }
  }
  if (isf32){
    __syncthreads();
    float* WsF = (float*)Ws;
    #pragma unroll
    for (int nt=0; nt<8; ++nt){
      float bv = b2f(wb[WB_PB + nt*16 + c]);
      #pragma unroll
      for (int r=0;r<4;++r)
        WsF[(wave*16 + 4*g + r)*128 + nt*16 + c] = acc[nt][r] + bv;
    }
    __syncthreads();
    const int tok = tid>>2, q4 = tid&3;
    int gtok = tokbase0 + tok;
    int win = gtok/392, tt = gtok - win*392;
    int dwi = win>>6, hwi = (win>>3)&7, wwi = win&7;
    int td = tt/49; int r2 = tt - td*49; int th = r2/7; int tw = r2 - th*7;
    int pd = dwi*8 + td + 4; if (pd >= 16) pd -= 16;
    int ph = hwi*7 + th + 3; if (ph >= 56) ph -= 56;
    int pwx = wwi*7 + tw + 3; if (pwx >= 56) pwx -= 56;
    size_t po = (size_t)((pd*56 + ph)*56 + pwx)*128;
    const float4* srcv = (const float4*)&WsF[tok*128 + q4*32];
    float4* dst = (float4*)((float*)out + po + q4*32);
    #pragma unroll
    for (int i=0;i<8;++i) dst[i] = srcv[i];
  } else {
    const int tokbase = tokbase0 + wave*16;
    size_t po[4];
    #pragma unroll
    for (int r=0;r<4;++r){
      int gtok = tokbase + 4*g + r;
      int win = gtok/392, tt = gtok - win*392;
      int dwi = win>>6, hwi = (win>>3)&7, wwi = win&7;
      int td = tt/49; int r2 = tt - td*49; int th = r2/7; int tw = r2 - th*7;
      int pd = dwi*8 + td + 4; if (pd >= 16) pd -= 16;
      int ph = hwi*7 + th + 3; if (ph >= 56) ph -= 56;
      int pwx = wwi*7 + tw + 3; if (pwx >= 56) pwx -= 56;
      po[r] = (size_t)((pd*56 + ph)*56 + pwx)*128;
    }
    #pragma unroll
    for (int nt=0; nt<8; ++nt){
      int oc = nt*16 + c;
      float bv = b2f(wb[WB_PB + oc]);
      #pragma unroll
      for (int r=0;r<4;++r)
        ((u16*)out)[po[r] + oc] = f2b(acc[nt][r] + bv);
    }
  }
}

extern "C" void kernel_launch(void* const* d_in, const int* in_sizes, int n_in,
                              void* d_out, int out_size, void* d_ws, size_t ws_size,
                              hipStream_t stream){
  const void* x      = d_in[0];
  const void* qkv_w  = d_in[1];
  const void* qkv_b  = d_in[2];
  const void* proj_w = d_in[3];
  const void* proj_b = d_in[4];
  const void* lsc    = d_in[5];
  const void* cpb_w1 = d_in[6];
  const void* cpb_b1 = d_in[7];
  const void* cpb_w2 = d_in[8];
  char* ws = (char*)d_ws;
  float* table16 = (float*)(ws);                     // 40,960 B
  float* bias16  = (float*)(ws + 40960);             // 2,458,624 B
  u16*   wb      = (u16*)(ws + 2499584);             // 132,096 B
  u16*   qkvbuf  = (u16*)(ws + 2631680);             // 38,535,168 B
  u16*   attnout = (u16*)(ws + 41166848);            // 12,845,056 B

  k_cpb <<<TBL, 64, 0, stream>>>(cpb_w1, cpb_b1, cpb_w2, x,
                                 qkv_w, proj_w, qkv_b, proj_b, wb, table16);
  k_bias<<<dim3(392,4), 128, 0, stream>>>(table16, bias16);
  k_qkv <<<784, 256, 0, stream>>>(x, wb, lsc, qkvbuf);
  k_attn<<<dim3(128,4), 512, 0, stream>>>(qkvbuf, bias16, attnout);
  k_proj<<<784, 256, 0, stream>>>(attnout, wb, x, d_out);
}